// Round 4
// baseline (365.946 us; speedup 1.0000x reference)
//
#include <hip/hip_runtime.h>
#include <stdint.h>

#define TT 8192          // sequence length T
#define BT 16384         // B*T tokens
#define MCH 8192         // token chunk for qkv GEMM + attention

typedef __attribute__((ext_vector_type(8))) __bf16 bf16x8;
typedef __attribute__((ext_vector_type(4))) __bf16 bf16x4;
typedef __attribute__((ext_vector_type(4))) short short4v;
typedef __attribute__((ext_vector_type(4))) float floatx4;

__device__ __forceinline__ float bf2f(unsigned short h) {
  union { unsigned u; float f; } x; x.u = ((unsigned)h) << 16; return x.f;
}
__device__ __forceinline__ unsigned short f2bf(float f) {
  union { float f; unsigned u; } x; x.f = f;
  unsigned r = (x.u + 0x7fffu + ((x.u >> 16) & 1u)) >> 16;
  return (unsigned short)r;
}
__device__ __forceinline__ void async16(const void* g, void* l) {
  __builtin_amdgcn_global_load_lds(
      (__attribute__((address_space(1))) void*)g,
      (__attribute__((address_space(3))) void*)l, 16, 0, 0);
}

// ---------------------------------------------------------------------------
// fp32 -> bf16 conversion (round-to-nearest-even), float4 vectorized.
// ---------------------------------------------------------------------------
__global__ __launch_bounds__(256) void cvt_f2b(
    const float* __restrict__ src, unsigned short* __restrict__ dst, int n4) {
  const int i = blockIdx.x * 256 + threadIdx.x;
  if (i < n4) {
    const float4 f = ((const float4*)src)[i];
    union { uint2 u2; unsigned short s[4]; } o;
    o.s[0] = f2bf(f.x); o.s[1] = f2bf(f.y);
    o.s[2] = f2bf(f.z); o.s[3] = f2bf(f.w);
    ((uint2*)dst)[i] = o.u2;
  }
}

// ---------------------------------------------------------------------------
// Weight pack: fp32 row-major W[Nr][K] -> bf16 MFMA-fragment order.
// 16B chunk c: lane l = c&63, g = c>>6, kt = g%NT, rb = g/NT.
// chunk holds W[rb*16 + (l&15)][kt*32 + (l>>4)*8 .. +8] as bf16x8.
// A wave's B-fragment load (16-row group rb, K-tile kt) is then one fully
// coalesced global_load_dwordx4 at (rb*NT+kt)*64 + lane.
// ---------------------------------------------------------------------------
__global__ __launch_bounds__(256) void pack_w(
    const float* __restrict__ src, uint4* __restrict__ dst, int nchunks,
    int K, int NT) {
  const int c = blockIdx.x * 256 + threadIdx.x;
  if (c >= nchunks) return;
  const int l  = c & 63;
  const int g  = c >> 6;
  const int kt = g % NT;
  const int rb = g / NT;
  const int row = rb * 16 + (l & 15);
  const int k0  = kt * 32 + (l >> 4) * 8;
  const float4 f0 = *(const float4*)(src + (size_t)row * K + k0);
  const float4 f1 = *(const float4*)(src + (size_t)row * K + k0 + 4);
  union { uint4 u4; unsigned short s[8]; } o;
  o.s[0] = f2bf(f0.x); o.s[1] = f2bf(f0.y); o.s[2] = f2bf(f0.z); o.s[3] = f2bf(f0.w);
  o.s[4] = f2bf(f1.x); o.s[5] = f2bf(f1.y); o.s[6] = f2bf(f1.z); o.s[7] = f2bf(f1.w);
  dst[c] = o.u4;
}

// ---------------------------------------------------------------------------
// RoPE cos/sin table: tab[t*32+p] = (cos, sin) of t * 10000^(-p/32)
// ---------------------------------------------------------------------------
__global__ __launch_bounds__(256) void rope_table_k(float2* __restrict__ tab) {
  const int i = blockIdx.x * 256 + threadIdx.x;
  if (i < TT * 32) {
    const int t = i >> 5, p = i & 31;
    const float f = (float)t * exp2f((float)p * -0.41524101186092f); // -log2(1e4)/32
    float s, c;
    sincosf(f, &s, &c);
    tab[i] = make_float2(c, s);
  }
}

// ---------------------------------------------------------------------------
// GEMM with B direct-from-packed-global: C[M,N] = A[M,K] . W[N,K]^T
// A staged in LDS ([256][32] x3 rotating bufs, 48 KiB, global_load_lds w=16,
// XOR chunk-swizzle on source + read side — proven 0-conflict). B fragments
// loaded straight to registers from fragment-packed Wp (coalesced 1KB/load,
// L1/L2-resident), register double-buffered. This halves LDS traffic: per CU
// per K32-tile ~48KB vs 932cyc MFMA -> MFMA-bound, not LDS-bound.
// 8 waves (4M x 2N), wave-tile 64 x (NWF*16); BM=256, BN=2*NWF*16.
// One barrier per K-tile; counted vmcnt(NWF+2) — never 0 mid-loop;
// JIT A-frag ds_read with lgkmcnt(0)+sched_barrier; setprio around MFMA.
// bn-major XCD block mapping keeps each XCD's B panels L2-resident.
// Requires: M%256==0, N%BN==0, K%32==0, K/32 even >=4, grid%8==0.
// ---------------------------------------------------------------------------
template <int NWF, bool CF32>
__global__ __launch_bounds__(512, 2) void gemm_bd(
    const unsigned short* __restrict__ A,
    const uint4* __restrict__ Wp,
    void* __restrict__ C,
    int M, int N, int K)
{
  __shared__ __align__(16) unsigned short smA[3 * 256 * 32];   // 48 KiB

  const int BN   = 2 * NWF * 16;
  const int tid  = threadIdx.x;
  const int lane = tid & 63;
  const int wid  = tid >> 6;          // 0..7
  const int wr   = wid >> 1;          // 0..3 : wave row (64 rows each)
  const int wcl  = wid & 1;           // 0..1 : wave col (NWF*16 cols each)
  const int lm   = lane & 15;
  const int kg   = lane >> 4;
  const int cxor = (lm >> 1) & 3;     // read-side swizzle ((row>>1)&3)

  // XCD swizzle, bn-major: consecutive same-XCD blocks share bn (B in L2).
  const int nbm = M >> 8;
  const int cpx = (int)gridDim.x >> 3;
  const int bid = blockIdx.x;
  const int swz = (bid & 7) * cpx + (bid >> 3);
  const int bm  = swz % nbm;
  const int bn  = swz / nbm;

  const int NT = K >> 5;              // K-tiles of 32

  // ---- A staging: 2 x async16 per thread per tile ----
  const unsigned short* gsrcA0;
  const unsigned short* gsrcA1;
  int ldso0, ldso1;
  {
    const int i0 = tid, i1 = 512 + tid;
    const int r0 = i0 >> 2, c0 = i0 & 3;
    const int r1 = i1 >> 2, c1 = i1 & 3;
    gsrcA0 = A + (size_t)(bm * 256 + r0) * (size_t)K + ((c0 ^ ((r0 >> 1) & 3)) << 3);
    gsrcA1 = A + (size_t)(bm * 256 + r1) * (size_t)K + ((c1 ^ ((r1 >> 1) & 3)) << 3);
    ldso0 = i0 * 8;                  // ushort offset (16B chunks)
    ldso1 = i1 * 8;
  }
#define STAGE_A(tt)                                                      \
  {                                                                      \
    unsigned short* d = smA + ((tt) % 3) * 8192;                         \
    async16(gsrcA0 + (size_t)(tt) * 32, d + ldso0);                      \
    async16(gsrcA1 + (size_t)(tt) * 32, d + ldso1);                      \
  }

  // ---- B fragment base pointers (packed layout) ----
  const int rbg0 = bn * (BN >> 4) + wcl * NWF;
  const uint4* WpJ[NWF];
#pragma unroll
  for (int j = 0; j < NWF; ++j)
    WpJ[j] = Wp + ((size_t)(rbg0 + j) * (size_t)NT) * 64 + lane;

  floatx4 acc[4][NWF];
  floatx4 z = {0.f, 0.f, 0.f, 0.f};
#pragma unroll
  for (int i = 0; i < 4; ++i)
#pragma unroll
    for (int j = 0; j < NWF; ++j) acc[i][j] = z;

  bf16x8 Bbuf0[NWF], Bbuf1[NWF];

  // ---- prologue: B(0) -> regs; stage A(0), A(1); gate A(0)+B(0) ----
#pragma unroll
  for (int j = 0; j < NWF; ++j)
    Bbuf0[j] = *(const bf16x8*)(WpJ[j]);
  STAGE_A(0);
  STAGE_A(1);
  asm volatile("s_waitcnt vmcnt(2)" ::: "memory");   // drain B(0), stage(0)
  __builtin_amdgcn_sched_barrier(0);

  // Per-iter t: barrier | ds_read A(t) | load B(t+1) | stage A(t+2) |
  //             vmcnt(NWF+2) | lgkmcnt(0) | MFMA.
  // One barrier/tile is safe: stage(t+2) writes buf[(t+2)%3]=buf[(t-1)%3],
  // whose reads completed before each wave's lgkmcnt(0) in iter t-1, which
  // precedes this iter's barrier.
#define SUBITER(T, BC, BNX)                                                   \
  {                                                                           \
    const int t_ = (T);                                                       \
    __builtin_amdgcn_s_barrier();                                             \
    const unsigned short* Ab = smA + (t_ % 3) * 8192;                         \
    bf16x8 afr[4];                                                            \
    _Pragma("unroll")                                                         \
    for (int i = 0; i < 4; ++i) {                                             \
      const int rr = wr * 64 + i * 16 + lm;                                   \
      afr[i] = *(const bf16x8*)(Ab + rr * 32 + ((kg ^ cxor) << 3));           \
    }                                                                         \
    if (t_ + 1 < NT) {                                                        \
      _Pragma("unroll")                                                       \
      for (int j = 0; j < NWF; ++j)                                           \
        BNX[j] = *(const bf16x8*)(WpJ[j] + (size_t)(t_ + 1) * 64);            \
    }                                                                         \
    if (t_ + 2 < NT) STAGE_A(t_ + 2);                                         \
    if (t_ + 2 < NT) {                                                        \
      if constexpr (NWF == 6)                                                 \
        asm volatile("s_waitcnt vmcnt(8)" ::: "memory");                      \
      else                                                                    \
        asm volatile("s_waitcnt vmcnt(6)" ::: "memory");                      \
    } else if (t_ + 1 < NT) {                                                 \
      if constexpr (NWF == 6)                                                 \
        asm volatile("s_waitcnt vmcnt(6)" ::: "memory");                      \
      else                                                                    \
        asm volatile("s_waitcnt vmcnt(4)" ::: "memory");                      \
    } else {                                                                  \
      asm volatile("s_waitcnt vmcnt(0)" ::: "memory");                        \
    }                                                                         \
    asm volatile("s_waitcnt lgkmcnt(0)" ::: "memory");                        \
    __builtin_amdgcn_sched_barrier(0);                                        \
    __builtin_amdgcn_s_setprio(1);                                            \
    _Pragma("unroll")                                                         \
    for (int i = 0; i < 4; ++i)                                               \
      _Pragma("unroll")                                                       \
      for (int j = 0; j < NWF; ++j)                                           \
        acc[i][j] = __builtin_amdgcn_mfma_f32_16x16x32_bf16(                  \
            afr[i], BC[j], acc[i][j], 0, 0, 0);                               \
    __builtin_amdgcn_s_setprio(0);                                            \
    __builtin_amdgcn_sched_barrier(0);                                        \
  }

  for (int t = 0; t < NT; t += 2) {
    SUBITER(t, Bbuf0, Bbuf1);
    SUBITER(t + 1, Bbuf1, Bbuf0);
  }
#undef SUBITER
#undef STAGE_A

  // ---- epilogue ----
#pragma unroll
  for (int i = 0; i < 4; ++i) {
    const int row0 = bm * 256 + wr * 64 + i * 16 + kg * 4;
#pragma unroll
    for (int j = 0; j < NWF; ++j) {
      const int col = bn * BN + wcl * (NWF * 16) + j * 16 + lm;
#pragma unroll
      for (int r = 0; r < 4; ++r) {
        if (CF32)
          ((float*)C)[(size_t)(row0 + r) * N + col] = acc[i][j][r];
        else
          ((unsigned short*)C)[(size_t)(row0 + r) * N + col] = f2bf(acc[i][j][r]);
      }
    }
  }
}

// ---------------------------------------------------------------------------
// MFMA-based per-token head-attention with fused RoPE (table-based).
// One wave per token (2 tokens / 128-thread block). Q/K/V staged as bf16
// rows [16][72] (b128 writes, conflict-free). Scores: S^T = K.Q^T via
// 2x mfma_16x16x32_bf16 -> s4[r] = S[lm][quad*4+r]. PV via mfma_16x16x16_bf16
// (P packed in-register; S^T C-layout == P A-layout) or lean VALU fallback.
// Output in transpose(0,2,1,3).reshape layout:
//   Y[b*8192 + qh*512 + t/16][(t&15)*64 + d]
// ---------------------------------------------------------------------------
#if defined(__has_builtin)
#if __has_builtin(__builtin_amdgcn_mfma_f32_16x16x16_bf16)
#define PV_MFMA 1
#define PV_MFMA_CALL(a, b, c) __builtin_amdgcn_mfma_f32_16x16x16_bf16( \
    *(bf16x4*)&(a), *(bf16x4*)&(b), (c), 0, 0, 0)
#elif __has_builtin(__builtin_amdgcn_mfma_f32_16x16x16bf16_1k)
#define PV_MFMA 1
#define PV_MFMA_CALL(a, b, c) __builtin_amdgcn_mfma_f32_16x16x16bf16_1k( \
    (a), (b), (c), 0, 0, 0)
#else
#define PV_MFMA 0
#endif
#else
#define PV_MFMA 0
#endif

__global__ __launch_bounds__(128) void attn_rope_k(
    const unsigned short* __restrict__ qkv,   // chunk-local, MCH tokens
    const float2* __restrict__ tab,
    unsigned short* __restrict__ Y,
    int base)
{
  // per-wave: Q [16][72], K [16][72], V [16][72] bf16 (pad 8 per row)
  __shared__ __align__(16) unsigned short sQKV[2][3 * 16 * 72];
#if !PV_MFMA
  __shared__ float sP[2][256];
#endif

  const int wave = threadIdx.x >> 6;
  const int lane = threadIdx.x & 63;
  const int ml = blockIdx.x * 2 + wave;  // chunk-local token
  const int m  = base + ml;              // global token
  const int t  = m & (TT - 1);
  const int b  = m >> 13;

  unsigned short* QB = sQKV[wave];            // Q rows
  unsigned short* KB = QB + 16 * 72;          // K rows
  unsigned short* VB = QB + 2 * 16 * 72;      // V rows

  const int lm   = lane & 15;
  const int quad = lane >> 4;

  // ---- staging: 6 x (b128 global read -> rope -> b128 LDS write) ----
  const uint4* row = (const uint4*)(qkv + (size_t)ml * 3072);
#pragma unroll
  for (int i = 0; i < 6; ++i) {
    const int c = lane + 64 * i;          // chunk of 8 bf16
    union { uint4 u4; unsigned short s[8]; } cv;
    cv.u4 = row[c];
    const int n0   = c * 8;
    const int part = n0 >> 10;            // 0=q 1=k 2=v (uniform per i)
    const int h    = (n0 >> 6) & 15;
    const int d0   = n0 & 63;
    if (part < 2) {
      float f[8];
#pragma unroll
      for (int j = 0; j < 8; ++j) f[j] = bf2f(cv.s[j]);
      const int p0 = d0 >> 1;
      const float4 csA = *(const float4*)(tab + (t << 5) + p0);
      const float4 csB = *(const float4*)(tab + (t << 5) + p0 + 2);
      const float cs[4] = {csA.x, csA.z, csB.x, csB.z};
      const float sn[4] = {csA.y, csA.w, csB.y, csB.w};
#pragma unroll
      for (int j = 0; j < 4; ++j) {
        const float x1 = f[2 * j], x2 = f[2 * j + 1];
        cv.s[2 * j]     = f2bf(x1 * cs[j] - x2 * sn[j]);
        cv.s[2 * j + 1] = f2bf(x2 * cs[j] + x1 * sn[j]);
      }
    }
    unsigned short* dst = QB + part * (16 * 72) + h * 72 + d0;
    *(uint4*)dst = cv.u4;
  }
  __syncthreads();

  // ---- scores: S^T = K . Q^T via 2x mfma_16x16x32 ----
  floatx4 accS = {0.f, 0.f, 0.f, 0.f};
#pragma unroll
  for (int half = 0; half < 2; ++half) {
    const bf16x8 kf = *(const bf16x8*)(KB + lm * 72 + half * 32 + quad * 8);
    const bf16x8 qf = *(const bf16x8*)(QB + lm * 72 + half * 32 + quad * 8);
    accS = __builtin_amdgcn_mfma_f32_16x16x32_bf16(kf, qf, accS, 0, 0, 0);
  }
  // accS[r] = S[q=lm][k=quad*4+r]
  float s4[4];
  float mx = -1e30f;
#pragma unroll
  for (int j = 0; j < 4; ++j) { s4[j] = accS[j] * 0.125f; mx = fmaxf(mx, s4[j]); }
  mx = fmaxf(mx, __shfl_xor(mx, 16, 64));
  mx = fmaxf(mx, __shfl_xor(mx, 32, 64));
  float sum = 0.f;
#pragma unroll
  for (int j = 0; j < 4; ++j) { s4[j] = __expf(s4[j] - mx); sum += s4[j]; }
  sum += __shfl_xor(sum, 16, 64);
  sum += __shfl_xor(sum, 32, 64);
  const float inv = 1.0f / sum;

#if PV_MFMA
  // ---- PV via mfma_16x16x16: A = P (in-register, S^T C-layout == A-layout)
  union { short4v v; unsigned short s[4]; } pf;
#pragma unroll
  for (int j = 0; j < 4; ++j) pf.s[j] = s4[j] * inv == 0.f ? 0 : f2bf(s4[j] * inv);
  // O[q=quad*4+r][dtile*16+lm]
#pragma unroll
  for (int dtile = 0; dtile < 4; ++dtile) {
    union { short4v v; unsigned short s[4]; } vf;
#pragma unroll
    for (int j = 0; j < 4; ++j)
      vf.s[j] = VB[(quad * 4 + j) * 72 + dtile * 16 + lm];
    floatx4 accO = {0.f, 0.f, 0.f, 0.f};
    accO = PV_MFMA_CALL(pf.v, vf.v, accO);
    const int col = (t & 15) * 64 + dtile * 16 + lm;
#pragma unroll
    for (int r = 0; r < 4; ++r) {
      const size_t rr = (size_t)b * TT + (size_t)(quad * 4 + r) * 512 + (t >> 4);
      Y[rr * 1024 + col] = f2bf(accO[r]);
    }
  }
#else
  // ---- VALU fallback: P via small LDS, V read as bf16 b128 ----
  float* P = sP[wave];
#pragma unroll
  for (int j = 0; j < 4; ++j) P[(quad * 4 + j) * 16 + lm] = s4[j] * inv;
  __syncthreads();
  float o[16];
#pragma unroll
  for (int dd = 0; dd < 16; ++dd) o[dd] = 0.f;
#pragma unroll
  for (int kh = 0; kh < 16; ++kh) {
    const float a = P[kh * 16 + lm];
    union { uint4 u4; unsigned short s[8]; } v0, v1;
    v0.u4 = *(const uint4*)(VB + kh * 72 + quad * 16);
    v1.u4 = *(const uint4*)(VB + kh * 72 + quad * 16 + 8);
#pragma unroll
    for (int dd = 0; dd < 8; ++dd) {
      o[dd]     += a * bf2f(v0.s[dd]);
      o[dd + 8] += a * bf2f(v1.s[dd]);
    }
  }
  const size_t rr = (size_t)b * TT + (size_t)lm * 512 + (t >> 4);
  unsigned short* yp = Y + rr * 1024 + (t & 15) * 64 + quad * 16;
  union { uint4 u4; unsigned short s[8]; } o1, o2;
#pragma unroll
  for (int dd = 0; dd < 8; ++dd) o1.s[dd] = f2bf(o[dd]);
#pragma unroll
  for (int dd = 0; dd < 8; ++dd) o2.s[dd] = f2bf(o[8 + dd]);
  ((uint4*)yp)[0] = o1.u4;
  ((uint4*)yp)[1] = o2.u4;
#endif
}

// ---------------------------------------------------------------------------
extern "C" void kernel_launch(void* const* d_in, const int* in_sizes, int n_in,
                              void* d_out, int out_size, void* d_ws, size_t ws_size,
                              hipStream_t stream) {
  const float* x    = (const float*)d_in[0];  // (2,8192,1024) fp32
  const float* Wqkv = (const float*)d_in[1];  // (3072,1024)  fp32
  const float* Wout = (const float*)d_in[2];  // (1024,1024)  fp32
  float* out = (float*)d_out;                 // (2,8192,1024) fp32

  // ws (56 MiB, proven): Y 32 | Wqkvp 6 | Woutp 2 | xb 16
  // d_out (67.1 MB): qkv chunk 50.3 MB at 0, rope table 2 MiB at +52 MiB.
  unsigned short* Y     = (unsigned short*)d_ws;
  unsigned short* Wqkvp = Y + (size_t)BT * 1024;       // packed qkv weights
  unsigned short* Woutp = Wqkvp + (size_t)3072 * 1024; // packed out weights
  unsigned short* xb    = Woutp + (size_t)1024 * 1024;
  unsigned short* qkvC  = (unsigned short*)d_out;
  float2* tab           = (float2*)((char*)d_out + (size_t)52 * 1024 * 1024);

  rope_table_k<<<dim3(TT * 32 / 256), dim3(256), 0, stream>>>(tab);
  pack_w<<<dim3(3072 * 1024 / 8 / 256), dim3(256), 0, stream>>>(
      Wqkv, (uint4*)Wqkvp, 3072 * 1024 / 8, 1024, 32);
  pack_w<<<dim3(1024 * 1024 / 8 / 256), dim3(256), 0, stream>>>(
      Wout, (uint4*)Woutp, 1024 * 1024 / 8, 1024, 32);

  for (int base = 0; base < BT; base += MCH) {
    cvt_f2b<<<dim3(MCH * 1024 / 4 / 256), dim3(256), 0, stream>>>(
        x + (size_t)base * 1024, xb, MCH * 1024 / 4);
    // BM=256, BN=192: grid 32x16 = 512 blocks = exactly 2 rounds, no tail
    gemm_bd<6, false><<<dim3((MCH / 256) * (3072 / 192)), dim3(512), 0, stream>>>(
        xb, (const uint4*)Wqkvp, qkvC, MCH, 3072, 1024);
    attn_rope_k<<<dim3(MCH / 2), dim3(128), 0, stream>>>(qkvC, tab, Y, base);
  }

  // out = Y @ Wout^T : M=16384, N=1024, K=1024 (fp32 output)
  // BM=256, BN=128: grid 64x8 = 512 blocks = exactly 2 rounds, no tail
  gemm_bd<4, true><<<dim3((BT / 256) * (1024 / 128)), dim3(512), 0, stream>>>(
      Y, (const uint4*)Woutp, out, BT, 1024, 1024);
}

// Round 5
// 314.462 us; speedup vs baseline: 1.1637x; 1.1637x over previous
//
#include <hip/hip_runtime.h>
#include <stdint.h>

#define TT 8192          // sequence length T
#define BT 16384         // B*T tokens
#define MCH 8192         // token chunk for qkv GEMM + attention

typedef __attribute__((ext_vector_type(8))) __bf16 bf16x8;
typedef __attribute__((ext_vector_type(4))) __bf16 bf16x4;
typedef __attribute__((ext_vector_type(4))) short short4v;
typedef __attribute__((ext_vector_type(4))) float floatx4;

__device__ __forceinline__ float bf2f(unsigned short h) {
  union { unsigned u; float f; } x; x.u = ((unsigned)h) << 16; return x.f;
}
__device__ __forceinline__ unsigned short f2bf(float f) {
  union { float f; unsigned u; } x; x.f = f;
  unsigned r = (x.u + 0x7fffu + ((x.u >> 16) & 1u)) >> 16;
  return (unsigned short)r;
}
__device__ __forceinline__ void async16(const void* g, void* l) {
  __builtin_amdgcn_global_load_lds(
      (__attribute__((address_space(1))) void*)g,
      (__attribute__((address_space(3))) void*)l, 16, 0, 0);
}

// ---------------------------------------------------------------------------
// fp32 -> bf16 conversion (round-to-nearest-even), float4 vectorized.
// ---------------------------------------------------------------------------
__global__ __launch_bounds__(256) void cvt_f2b(
    const float* __restrict__ src, unsigned short* __restrict__ dst, int n4) {
  const int i = blockIdx.x * 256 + threadIdx.x;
  if (i < n4) {
    const float4 f = ((const float4*)src)[i];
    union { uint2 u2; unsigned short s[4]; } o;
    o.s[0] = f2bf(f.x); o.s[1] = f2bf(f.y);
    o.s[2] = f2bf(f.z); o.s[3] = f2bf(f.w);
    ((uint2*)dst)[i] = o.u2;
  }
}

// ---------------------------------------------------------------------------
// RoPE cos/sin table: tab[t*32+p] = (cos, sin) of t * 10000^(-p/32)
// ---------------------------------------------------------------------------
__global__ __launch_bounds__(256) void rope_table_k(float2* __restrict__ tab) {
  const int i = blockIdx.x * 256 + threadIdx.x;
  if (i < TT * 32) {
    const int t = i >> 5, p = i & 31;
    const float f = (float)t * exp2f((float)p * -0.41524101186092f); // -log2(1e4)/32
    float s, c;
    sincosf(f, &s, &c);
    tab[i] = make_float2(c, s);
  }
}

// ---------------------------------------------------------------------------
// GEMM, occupancy-first pipelined schedule (round-2 exact — best measured):
// C[M,N] = A[M,K] . W[N,K]^T
// BM=256, BN=128, BK=32, 8 waves (4M x 2N), wave-tile 64x64 (acc[4][4]),
// LDS 48 KiB double-buffered, __launch_bounds__(512,4) capping regs so
// 2 blocks/CU (16 waves) fit. One phase per K-tile:
// {8x ds_read_b128 -> barrier -> lgkmcnt(0) -> stage(t+2, 3x gload_lds)
//  -> setprio(1) 16x MFMA setprio(0) -> vmcnt(3) -> barrier}.
// Counted vmcnt(3) keeps the next tile's loads in flight across barriers.
// XOR swizzle chunk ^= (row>>1)&3 on both stage-source and ds_read addr
// (measured 0 bank conflicts). XCD-aware blockIdx swizzle.
// Requires: M%256==0, N%128==0, K%32==0, K/32>=2, grid%8==0.
// ---------------------------------------------------------------------------
template <bool CF32>
__global__ __launch_bounds__(512, 4) void gemm_k32(
    const unsigned short* __restrict__ A,
    const unsigned short* __restrict__ W,
    void* __restrict__ C,
    int M, int N, int K)
{
  // per buf: A [256][32] (16 KB) + B [128][32] (8 KB) = 24 KB; x2 = 48 KiB
  __shared__ __align__(16) unsigned short sm[2][(256 + 128) * 32];

  const int tid  = threadIdx.x;
  const int lane = tid & 63;
  const int wid  = tid >> 6;
  const int wr   = wid >> 1;          // 0..3 : wave row (M, 64 rows each)
  const int wc   = wid & 1;           // 0..1 : wave col (N, 64 cols each)
  const int lm   = lane & 15;
  const int kg   = lane >> 4;
  const int cxor = (lm >> 1) & 3;     // read-side swizzle term ((row>>1)&3)

  // XCD-aware swizzle (grid % 8 == 0 for both call sites -> bijective)
  const int nb  = N >> 7;
  const int cpx = (int)gridDim.x >> 3;
  const int bid = blockIdx.x;
  const int swz = (bid & 7) * cpx + (bid >> 3);
  const int bm  = swz / nb;
  const int bn  = swz % nb;

  const int NT = K >> 5;              // K-tiles of 32

  // ---- staging geometry: 3 x global_load_lds(16B) per wave per tile ----
  const int sr  = lane >> 2;
  const int scb = lane & 3;
  const unsigned short* gsrc0;
  const unsigned short* gsrc1;
  const unsigned short* gsrc2;
  {
    const int r0 = wid * 16 + sr;          // 0..127
    const int r1 = 128 + r0;               // 128..255
    const int rB = wid * 16 + sr;          // 0..127
    gsrc0 = A + (size_t)(bm * 256 + r0) * (size_t)K + ((scb ^ ((r0 >> 1) & 3)) << 3);
    gsrc1 = A + (size_t)(bm * 256 + r1) * (size_t)K + ((scb ^ ((r1 >> 1) & 3)) << 3);
    gsrc2 = W + (size_t)(bn * 128 + rB) * (size_t)K + ((scb ^ ((rB >> 1) & 3)) << 3);
  }
  const int ld0 = wid * 1024;              // A half 0
  const int ld1 = 8192 + wid * 1024;       // A half 1
  const int ld2 = 16384 + wid * 1024;      // B

  auto stage_tile = [&](int tt) {
    char* lb = (char*)sm[tt & 1];
    const size_t koff = (size_t)tt << 5;   // element offset along K
    async16(gsrc0 + koff, lb + ld0);
    async16(gsrc1 + koff, lb + ld1);
    async16(gsrc2 + koff, lb + ld2);
  };

  floatx4 acc[4][4];
  floatx4 z = {0.f, 0.f, 0.f, 0.f};
#pragma unroll
  for (int i = 0; i < 4; ++i)
#pragma unroll
    for (int j = 0; j < 4; ++j) acc[i][j] = z;

  // ---- prologue: tiles 0 and 1 in flight; gate on tile-0 residency ----
  stage_tile(0);
  stage_tile(1);
  asm volatile("s_waitcnt vmcnt(3)" ::: "memory");
  __builtin_amdgcn_s_barrier();
  __builtin_amdgcn_sched_barrier(0);

  for (int t = 0; t < NT; ++t) {
    const unsigned short* Ab = sm[t & 1];
    const unsigned short* Bb = Ab + 256 * 32;

    bf16x8 af[4], bfr[4];
#pragma unroll
    for (int i = 0; i < 4; ++i) {
      const int rr = wr * 64 + i * 16 + lm;
      af[i] = *(const bf16x8*)(Ab + rr * 32 + ((kg ^ cxor) << 3));
    }
#pragma unroll
    for (int j = 0; j < 4; ++j) {
      const int rr = wc * 64 + j * 16 + lm;
      bfr[j] = *(const bf16x8*)(Bb + rr * 32 + ((kg ^ cxor) << 3));
    }

    // all waves' reads of this tile issued before anyone overwrites the buf
    __builtin_amdgcn_s_barrier();
    asm volatile("s_waitcnt lgkmcnt(0)" ::: "memory");
    __builtin_amdgcn_sched_barrier(0);

    if (t + 2 < NT) stage_tile(t + 2);   // overwrites buf just consumed

    __builtin_amdgcn_s_setprio(1);
#pragma unroll
    for (int i = 0; i < 4; ++i)
#pragma unroll
      for (int j = 0; j < 4; ++j)
        acc[i][j] = __builtin_amdgcn_mfma_f32_16x16x32_bf16(
            af[i], bfr[j], acc[i][j], 0, 0, 0);
    __builtin_amdgcn_s_setprio(0);

    if (t + 1 < NT) {
      // gate: tile t+1 resident; tile t+2's 3 loads may stay in flight.
      if (t + 2 < NT)
        asm volatile("s_waitcnt vmcnt(3)" ::: "memory");
      else
        asm volatile("s_waitcnt vmcnt(0)" ::: "memory");
      __builtin_amdgcn_s_barrier();
      __builtin_amdgcn_sched_barrier(0);
    }
  }

  // ---- epilogue ----
#pragma unroll
  for (int i = 0; i < 4; ++i) {
    const int row0 = bm * 256 + wr * 64 + i * 16 + kg * 4;
#pragma unroll
    for (int j = 0; j < 4; ++j) {
      const int col = bn * 128 + wc * 64 + j * 16 + lm;
#pragma unroll
      for (int r = 0; r < 4; ++r) {
        if (CF32)
          ((float*)C)[(size_t)(row0 + r) * N + col] = acc[i][j][r];
        else
          ((unsigned short*)C)[(size_t)(row0 + r) * N + col] = f2bf(acc[i][j][r]);
      }
    }
  }
}

// ---------------------------------------------------------------------------
// MFMA-based per-token head-attention with fused RoPE (table-based).
// One wave per token, 4 tokens / 256-thread block (fewer dispatoch units than
// the 2-token version; each wave touches ONLY its own LDS slice, so the
// cross-wave __syncthreads is replaced by a wave-local lgkmcnt(0) drain).
// Q/K/V staged as bf16 rows [16][72] (b128 writes, conflict-free).
// Scores: S^T = K.Q^T via 2x mfma_16x16x32_bf16 -> s4[r] = S[lm][quad*4+r].
// PV via mfma_16x16x16_bf16 (P packed in-register; S^T C-layout == P
// A-layout) or lean VALU fallback. Output in transpose(0,2,1,3) layout:
//   Y[b*8192 + qh*512 + t/16][(t&15)*64 + d]
// ---------------------------------------------------------------------------
#if defined(__has_builtin)
#if __has_builtin(__builtin_amdgcn_mfma_f32_16x16x16_bf16)
#define PV_MFMA 1
#define PV_MFMA_CALL(a, b, c) __builtin_amdgcn_mfma_f32_16x16x16_bf16( \
    *(bf16x4*)&(a), *(bf16x4*)&(b), (c), 0, 0, 0)
#elif __has_builtin(__builtin_amdgcn_mfma_f32_16x16x16bf16_1k)
#define PV_MFMA 1
#define PV_MFMA_CALL(a, b, c) __builtin_amdgcn_mfma_f32_16x16x16bf16_1k( \
    (a), (b), (c), 0, 0, 0)
#else
#define PV_MFMA 0
#endif
#else
#define PV_MFMA 0
#endif

__global__ __launch_bounds__(256) void attn_rope_k(
    const unsigned short* __restrict__ qkv,   // chunk-local, MCH tokens
    const float2* __restrict__ tab,
    unsigned short* __restrict__ Y,
    int base)
{
  // per-wave: Q [16][72], K [16][72], V [16][72] bf16 (pad 8 per row)
  __shared__ __align__(16) unsigned short sQKV[4][3 * 16 * 72];
#if !PV_MFMA
  __shared__ float sP[4][256];
#endif

  const int wave = threadIdx.x >> 6;
  const int lane = threadIdx.x & 63;
  const int ml = blockIdx.x * 4 + wave;  // chunk-local token
  const int m  = base + ml;              // global token
  const int t  = m & (TT - 1);
  const int b  = m >> 13;

  unsigned short* QB = sQKV[wave];            // Q rows
  unsigned short* KB = QB + 16 * 72;          // K rows
  unsigned short* VB = QB + 2 * 16 * 72;      // V rows

  const int lm   = lane & 15;
  const int quad = lane >> 4;

  // ---- staging: 6 x (b128 global read -> rope -> b128 LDS write) ----
  const uint4* row = (const uint4*)(qkv + (size_t)ml * 3072);
#pragma unroll
  for (int i = 0; i < 6; ++i) {
    const int c = lane + 64 * i;          // chunk of 8 bf16
    union { uint4 u4; unsigned short s[8]; } cv;
    cv.u4 = row[c];
    const int n0   = c * 8;
    const int part = n0 >> 10;            // 0=q 1=k 2=v (uniform per i)
    const int h    = (n0 >> 6) & 15;
    const int d0   = n0 & 63;
    if (part < 2) {
      float f[8];
#pragma unroll
      for (int j = 0; j < 8; ++j) f[j] = bf2f(cv.s[j]);
      const int p0 = d0 >> 1;
      const float4 csA = *(const float4*)(tab + (t << 5) + p0);
      const float4 csB = *(const float4*)(tab + (t << 5) + p0 + 2);
      const float cs[4] = {csA.x, csA.z, csB.x, csB.z};
      const float sn[4] = {csA.y, csA.w, csB.y, csB.w};
#pragma unroll
      for (int j = 0; j < 4; ++j) {
        const float x1 = f[2 * j], x2 = f[2 * j + 1];
        cv.s[2 * j]     = f2bf(x1 * cs[j] - x2 * sn[j]);
        cv.s[2 * j + 1] = f2bf(x2 * cs[j] + x1 * sn[j]);
      }
    }
    unsigned short* dst = QB + part * (16 * 72) + h * 72 + d0;
    *(uint4*)dst = cv.u4;
  }
  // wave-local LDS drain (each wave reads only its own slice — no barrier)
  asm volatile("s_waitcnt lgkmcnt(0)" ::: "memory");
  __builtin_amdgcn_sched_barrier(0);

  // ---- scores: S^T = K . Q^T via 2x mfma_16x16x32 ----
  floatx4 accS = {0.f, 0.f, 0.f, 0.f};
#pragma unroll
  for (int half = 0; half < 2; ++half) {
    const bf16x8 kf = *(const bf16x8*)(KB + lm * 72 + half * 32 + quad * 8);
    const bf16x8 qf = *(const bf16x8*)(QB + lm * 72 + half * 32 + quad * 8);
    accS = __builtin_amdgcn_mfma_f32_16x16x32_bf16(kf, qf, accS, 0, 0, 0);
  }
  // accS[r] = S[q=lm][k=quad*4+r]
  float s4[4];
  float mx = -1e30f;
#pragma unroll
  for (int j = 0; j < 4; ++j) { s4[j] = accS[j] * 0.125f; mx = fmaxf(mx, s4[j]); }
  mx = fmaxf(mx, __shfl_xor(mx, 16, 64));
  mx = fmaxf(mx, __shfl_xor(mx, 32, 64));
  float sum = 0.f;
#pragma unroll
  for (int j = 0; j < 4; ++j) { s4[j] = __expf(s4[j] - mx); sum += s4[j]; }
  sum += __shfl_xor(sum, 16, 64);
  sum += __shfl_xor(sum, 32, 64);
  const float inv = 1.0f / sum;

#if PV_MFMA
  // ---- PV via mfma_16x16x16: A = P (in-register, S^T C-layout == A-layout)
  union { short4v v; unsigned short s[4]; } pf;
#pragma unroll
  for (int j = 0; j < 4; ++j) pf.s[j] = s4[j] * inv == 0.f ? 0 : f2bf(s4[j] * inv);
  // O[q=quad*4+r][dtile*16+lm]
#pragma unroll
  for (int dtile = 0; dtile < 4; ++dtile) {
    union { short4v v; unsigned short s[4]; } vf;
#pragma unroll
    for (int j = 0; j < 4; ++j)
      vf.s[j] = VB[(quad * 4 + j) * 72 + dtile * 16 + lm];
    floatx4 accO = {0.f, 0.f, 0.f, 0.f};
    accO = PV_MFMA_CALL(pf.v, vf.v, accO);
    const int col = (t & 15) * 64 + dtile * 16 + lm;
#pragma unroll
    for (int r = 0; r < 4; ++r) {
      const size_t rr = (size_t)b * TT + (size_t)(quad * 4 + r) * 512 + (t >> 4);
      Y[rr * 1024 + col] = f2bf(accO[r]);
    }
  }
#else
  // ---- VALU fallback: P via small LDS, V read as bf16 b128 ----
  float* P = sP[wave];
#pragma unroll
  for (int j = 0; j < 4; ++j) P[(quad * 4 + j) * 16 + lm] = s4[j] * inv;
  __syncthreads();
  float o[16];
#pragma unroll
  for (int dd = 0; dd < 16; ++dd) o[dd] = 0.f;
#pragma unroll
  for (int kh = 0; kh < 16; ++kh) {
    const float a = P[kh * 16 + lm];
    union { uint4 u4; unsigned short s[8]; } v0, v1;
    v0.u4 = *(const uint4*)(VB + kh * 72 + quad * 16);
    v1.u4 = *(const uint4*)(VB + kh * 72 + quad * 16 + 8);
#pragma unroll
    for (int dd = 0; dd < 8; ++dd) {
      o[dd]     += a * bf2f(v0.s[dd]);
      o[dd + 8] += a * bf2f(v1.s[dd]);
    }
  }
  const size_t rr = (size_t)b * TT + (size_t)lm * 512 + (t >> 4);
  unsigned short* yp = Y + rr * 1024 + (t & 15) * 64 + quad * 16;
  union { uint4 u4; unsigned short s[8]; } o1, o2;
#pragma unroll
  for (int dd = 0; dd < 8; ++dd) o1.s[dd] = f2bf(o[dd]);
#pragma unroll
  for (int dd = 0; dd < 8; ++dd) o2.s[dd] = f2bf(o[8 + dd]);
  ((uint4*)yp)[0] = o1.u4;
  ((uint4*)yp)[1] = o2.u4;
#endif
}

// ---------------------------------------------------------------------------
extern "C" void kernel_launch(void* const* d_in, const int* in_sizes, int n_in,
                              void* d_out, int out_size, void* d_ws, size_t ws_size,
                              hipStream_t stream) {
  const float* x    = (const float*)d_in[0];  // (2,8192,1024) fp32
  const float* Wqkv = (const float*)d_in[1];  // (3072,1024)  fp32
  const float* Wout = (const float*)d_in[2];  // (1024,1024)  fp32
  float* out = (float*)d_out;                 // (2,8192,1024) fp32

  // ws (56 MiB, proven): Y 32 | Wqkvb 6 | Woutb 2 | xb 16
  // d_out (67.1 MB): qkv chunk 50.3 MB at 0, rope table 2 MiB at +52 MiB.
  unsigned short* Y     = (unsigned short*)d_ws;
  unsigned short* Wqkvb = Y + (size_t)BT * 1024;
  unsigned short* Woutb = Wqkvb + (size_t)3072 * 1024;
  unsigned short* xb    = Woutb + (size_t)1024 * 1024;
  unsigned short* qkvC  = (unsigned short*)d_out;
  float2* tab           = (float2*)((char*)d_out + (size_t)52 * 1024 * 1024);

  rope_table_k<<<dim3(TT * 32 / 256), dim3(256), 0, stream>>>(tab);
  cvt_f2b<<<dim3(3072 * 1024 / 4 / 256), dim3(256), 0, stream>>>(Wqkv, Wqkvb, 3072 * 1024 / 4);
  cvt_f2b<<<dim3(1024 * 1024 / 4 / 256), dim3(256), 0, stream>>>(Wout, Woutb, 1024 * 1024 / 4);

  for (int base = 0; base < BT; base += MCH) {
    cvt_f2b<<<dim3(MCH * 1024 / 4 / 256), dim3(256), 0, stream>>>(
        x + (size_t)base * 1024, xb, MCH * 1024 / 4);
    gemm_k32<false><<<dim3((MCH / 256) * (3072 / 128)), dim3(512), 0, stream>>>(
        xb, Wqkvb, qkvC, MCH, 3072, 1024);
    attn_rope_k<<<dim3(MCH / 4), dim3(256), 0, stream>>>(qkvC, tab, Y, base);
  }

  // out = Y @ Wout^T : M=16384, N=1024, K=1024 (fp32 output)
  gemm_k32<true><<<dim3((BT / 256) * (1024 / 128)), dim3(512), 0, stream>>>(
      Y, Woutb, out, BT, 1024, 1024);
}

// Round 6
// 310.078 us; speedup vs baseline: 1.1802x; 1.0141x over previous
//
#include <hip/hip_runtime.h>
#include <stdint.h>

#define TT 8192          // sequence length T
#define BT 16384         // B*T tokens
#define MCH 8192         // token chunk for qkv GEMM + attention

typedef __attribute__((ext_vector_type(8))) __bf16 bf16x8;
typedef __attribute__((ext_vector_type(4))) __bf16 bf16x4;
typedef __attribute__((ext_vector_type(4))) short short4v;
typedef __attribute__((ext_vector_type(4))) float floatx4;

__device__ __forceinline__ float bf2f(unsigned short h) {
  union { unsigned u; float f; } x; x.u = ((unsigned)h) << 16; return x.f;
}
__device__ __forceinline__ unsigned short f2bf(float f) {
  union { float f; unsigned u; } x; x.f = f;
  unsigned r = (x.u + 0x7fffu + ((x.u >> 16) & 1u)) >> 16;
  return (unsigned short)r;
}
__device__ __forceinline__ void async16(const void* g, void* l) {
  __builtin_amdgcn_global_load_lds(
      (__attribute__((address_space(1))) void*)g,
      (__attribute__((address_space(3))) void*)l, 16, 0, 0);
}

// ---------------------------------------------------------------------------
// fp32 -> bf16 conversion (round-to-nearest-even), float4 vectorized.
// ---------------------------------------------------------------------------
__global__ __launch_bounds__(256) void cvt_f2b(
    const float* __restrict__ src, unsigned short* __restrict__ dst, int n4) {
  const int i = blockIdx.x * 256 + threadIdx.x;
  if (i < n4) {
    const float4 f = ((const float4*)src)[i];
    union { uint2 u2; unsigned short s[4]; } o;
    o.s[0] = f2bf(f.x); o.s[1] = f2bf(f.y);
    o.s[2] = f2bf(f.z); o.s[3] = f2bf(f.w);
    ((uint2*)dst)[i] = o.u2;
  }
}

// ---------------------------------------------------------------------------
// Merged prep: RoPE table + Wqkv cvt + Wout cvt in one dispatch.
// blocks [0,1024): tab[t*32+p] = (cos,sin) of t * 10000^(-p/32)
// blocks [1024,4096): Wqkv fp32->bf16 (786432 float4s)
// blocks [4096,5120): Wout fp32->bf16 (262144 float4s)
// ---------------------------------------------------------------------------
__global__ __launch_bounds__(256) void prep_k(
    const float* __restrict__ Wqkv, const float* __restrict__ Wout,
    unsigned short* __restrict__ Wqkvb, unsigned short* __restrict__ Woutb,
    float2* __restrict__ tab) {
  const int bx = blockIdx.x;
  const int tid = threadIdx.x;
  if (bx < 1024) {
    const int i = bx * 256 + tid;
    const int t = i >> 5, p = i & 31;
    const float f = (float)t * exp2f((float)p * -0.41524101186092f); // -log2(1e4)/32
    float s, c;
    sincosf(f, &s, &c);
    tab[i] = make_float2(c, s);
  } else {
    const float* src;
    unsigned short* dst;
    int i;
    if (bx < 4096) { src = Wqkv; dst = Wqkvb; i = (bx - 1024) * 256 + tid; }
    else           { src = Wout; dst = Woutb; i = (bx - 4096) * 256 + tid; }
    const float4 f = ((const float4*)src)[i];
    union { uint2 u2; unsigned short s[4]; } o;
    o.s[0] = f2bf(f.x); o.s[1] = f2bf(f.y);
    o.s[2] = f2bf(f.z); o.s[3] = f2bf(f.w);
    ((uint2*)dst)[i] = o.u2;
  }
}

// ---------------------------------------------------------------------------
// GEMM, occupancy-first pipelined schedule (round-2 exact — best measured):
// C[M,N] = A[M,K] . W[N,K]^T
// BM=256, BN=128, BK=32, 8 waves (4M x 2N), wave-tile 64x64 (acc[4][4]),
// LDS 48 KiB double-buffered, __launch_bounds__(512,4) capping regs so
// 2 blocks/CU (16 waves) fit. One phase per K-tile:
// {8x ds_read_b128 -> barrier -> lgkmcnt(0) -> stage(t+2, 3x gload_lds)
//  -> setprio(1) 16x MFMA setprio(0) -> vmcnt(3) -> barrier}.
// Counted vmcnt(3) keeps the next tile's loads in flight across barriers.
// XOR swizzle chunk ^= (row>>1)&3 on both stage-source and ds_read addr
// (measured 0 bank conflicts). XCD-aware blockIdx swizzle.
// Requires: M%256==0, N%128==0, K%32==0, K/32>=2, grid%8==0.
// ---------------------------------------------------------------------------
template <bool CF32>
__global__ __launch_bounds__(512, 4) void gemm_k32(
    const unsigned short* __restrict__ A,
    const unsigned short* __restrict__ W,
    void* __restrict__ C,
    int M, int N, int K)
{
  // per buf: A [256][32] (16 KB) + B [128][32] (8 KB) = 24 KB; x2 = 48 KiB
  __shared__ __align__(16) unsigned short sm[2][(256 + 128) * 32];

  const int tid  = threadIdx.x;
  const int lane = tid & 63;
  const int wid  = tid >> 6;
  const int wr   = wid >> 1;          // 0..3 : wave row (M, 64 rows each)
  const int wc   = wid & 1;           // 0..1 : wave col (N, 64 cols each)
  const int lm   = lane & 15;
  const int kg   = lane >> 4;
  const int cxor = (lm >> 1) & 3;     // read-side swizzle term ((row>>1)&3)

  // XCD-aware swizzle (grid % 8 == 0 for both call sites -> bijective)
  const int nb  = N >> 7;
  const int cpx = (int)gridDim.x >> 3;
  const int bid = blockIdx.x;
  const int swz = (bid & 7) * cpx + (bid >> 3);
  const int bm  = swz / nb;
  const int bn  = swz % nb;

  const int NT = K >> 5;              // K-tiles of 32

  // ---- staging geometry: 3 x global_load_lds(16B) per wave per tile ----
  const int sr  = lane >> 2;
  const int scb = lane & 3;
  const unsigned short* gsrc0;
  const unsigned short* gsrc1;
  const unsigned short* gsrc2;
  {
    const int r0 = wid * 16 + sr;          // 0..127
    const int r1 = 128 + r0;               // 128..255
    const int rB = wid * 16 + sr;          // 0..127
    gsrc0 = A + (size_t)(bm * 256 + r0) * (size_t)K + ((scb ^ ((r0 >> 1) & 3)) << 3);
    gsrc1 = A + (size_t)(bm * 256 + r1) * (size_t)K + ((scb ^ ((r1 >> 1) & 3)) << 3);
    gsrc2 = W + (size_t)(bn * 128 + rB) * (size_t)K + ((scb ^ ((rB >> 1) & 3)) << 3);
  }
  const int ld0 = wid * 1024;              // A half 0
  const int ld1 = 8192 + wid * 1024;       // A half 1
  const int ld2 = 16384 + wid * 1024;      // B

  auto stage_tile = [&](int tt) {
    char* lb = (char*)sm[tt & 1];
    const size_t koff = (size_t)tt << 5;   // element offset along K
    async16(gsrc0 + koff, lb + ld0);
    async16(gsrc1 + koff, lb + ld1);
    async16(gsrc2 + koff, lb + ld2);
  };

  floatx4 acc[4][4];
  floatx4 z = {0.f, 0.f, 0.f, 0.f};
#pragma unroll
  for (int i = 0; i < 4; ++i)
#pragma unroll
    for (int j = 0; j < 4; ++j) acc[i][j] = z;

  // ---- prologue: tiles 0 and 1 in flight; gate on tile-0 residency ----
  stage_tile(0);
  stage_tile(1);
  asm volatile("s_waitcnt vmcnt(3)" ::: "memory");
  __builtin_amdgcn_s_barrier();
  __builtin_amdgcn_sched_barrier(0);

  for (int t = 0; t < NT; ++t) {
    const unsigned short* Ab = sm[t & 1];
    const unsigned short* Bb = Ab + 256 * 32;

    bf16x8 af[4], bfr[4];
#pragma unroll
    for (int i = 0; i < 4; ++i) {
      const int rr = wr * 64 + i * 16 + lm;
      af[i] = *(const bf16x8*)(Ab + rr * 32 + ((kg ^ cxor) << 3));
    }
#pragma unroll
    for (int j = 0; j < 4; ++j) {
      const int rr = wc * 64 + j * 16 + lm;
      bfr[j] = *(const bf16x8*)(Bb + rr * 32 + ((kg ^ cxor) << 3));
    }

    // all waves' reads of this tile issued before anyone overwrites the buf
    __builtin_amdgcn_s_barrier();
    asm volatile("s_waitcnt lgkmcnt(0)" ::: "memory");
    __builtin_amdgcn_sched_barrier(0);

    if (t + 2 < NT) stage_tile(t + 2);   // overwrites buf just consumed

    __builtin_amdgcn_s_setprio(1);
#pragma unroll
    for (int i = 0; i < 4; ++i)
#pragma unroll
      for (int j = 0; j < 4; ++j)
        acc[i][j] = __builtin_amdgcn_mfma_f32_16x16x32_bf16(
            af[i], bfr[j], acc[i][j], 0, 0, 0);
    __builtin_amdgcn_s_setprio(0);

    if (t + 1 < NT) {
      // gate: tile t+1 resident; tile t+2's 3 loads may stay in flight.
      if (t + 2 < NT)
        asm volatile("s_waitcnt vmcnt(3)" ::: "memory");
      else
        asm volatile("s_waitcnt vmcnt(0)" ::: "memory");
      __builtin_amdgcn_s_barrier();
      __builtin_amdgcn_sched_barrier(0);
    }
  }

  // ---- epilogue ----
#pragma unroll
  for (int i = 0; i < 4; ++i) {
    const int row0 = bm * 256 + wr * 64 + i * 16 + kg * 4;
#pragma unroll
    for (int j = 0; j < 4; ++j) {
      const int col = bn * 128 + wc * 64 + j * 16 + lm;
#pragma unroll
      for (int r = 0; r < 4; ++r) {
        if (CF32)
          ((float*)C)[(size_t)(row0 + r) * N + col] = acc[i][j][r];
        else
          ((unsigned short*)C)[(size_t)(row0 + r) * N + col] = f2bf(acc[i][j][r]);
      }
    }
  }
}

// ---------------------------------------------------------------------------
// MFMA-based per-token head-attention with fused RoPE (table-based).
// TWO tokens per wave (ILP2): the token's whole pipeline (global load ->
// RoPE -> LDS -> QK MFMA -> softmax shfl-reduce -> PV MFMA -> store) is a
// deep serial chain; pairing two independent tokens per wave lets the
// compiler interleave the two chains and hide latency. 2 waves / 128-thr
// block = 4 tokens/block; each wave touches only its own LDS slices, so
// cross-wave barriers are replaced by a wave-local lgkmcnt(0) drain.
// Q/K/V staged as bf16 rows [16][72] (b128 writes, conflict-free).
// Scores: S^T = K.Q^T via 2x mfma_16x16x32_bf16 -> s4[r] = S[lm][quad*4+r].
// PV via mfma_16x16x16_bf16 (P packed in-register; S^T C-layout == P
// A-layout) or lean VALU fallback. Output in transpose(0,2,1,3) layout:
//   Y[b*8192 + qh*512 + t/16][(t&15)*64 + d]
// ---------------------------------------------------------------------------
#if defined(__has_builtin)
#if __has_builtin(__builtin_amdgcn_mfma_f32_16x16x16_bf16)
#define PV_MFMA 1
#define PV_MFMA_CALL(a, b, c) __builtin_amdgcn_mfma_f32_16x16x16_bf16( \
    *(bf16x4*)&(a), *(bf16x4*)&(b), (c), 0, 0, 0)
#elif __has_builtin(__builtin_amdgcn_mfma_f32_16x16x16bf16_1k)
#define PV_MFMA 1
#define PV_MFMA_CALL(a, b, c) __builtin_amdgcn_mfma_f32_16x16x16bf16_1k( \
    (a), (b), (c), 0, 0, 0)
#else
#define PV_MFMA 0
#endif
#else
#define PV_MFMA 0
#endif

__global__ __launch_bounds__(128) void attn_rope_k(
    const unsigned short* __restrict__ qkv,   // chunk-local, MCH tokens
    const float2* __restrict__ tab,
    unsigned short* __restrict__ Y,
    int base)
{
  // per wave x token: Q [16][72], K [16][72], V [16][72] bf16 (pad 8/row)
  __shared__ __align__(16) unsigned short sQKV[2][2][3 * 16 * 72];
#if !PV_MFMA
  __shared__ float sP[2][2][256];
#endif

  const int wave = threadIdx.x >> 6;
  const int lane = threadIdx.x & 63;
  const int ml0  = blockIdx.x * 4 + wave * 2;  // first chunk-local token
  const int lm   = lane & 15;
  const int quad = lane >> 4;

  int tA[2], bA[2];
#pragma unroll
  for (int tk = 0; tk < 2; ++tk) {
    const int m = base + ml0 + tk;
    tA[tk] = m & (TT - 1);
    bA[tk] = m >> 13;
  }

  // ---- staging both tokens: 12 x (b128 global -> rope -> b128 LDS) ----
#pragma unroll
  for (int tk = 0; tk < 2; ++tk) {
    const uint4* row = (const uint4*)(qkv + (size_t)(ml0 + tk) * 3072);
    const int t = tA[tk];
    unsigned short* QB = sQKV[wave][tk];
#pragma unroll
    for (int i = 0; i < 6; ++i) {
      const int c = lane + 64 * i;          // chunk of 8 bf16
      union { uint4 u4; unsigned short s[8]; } cv;
      cv.u4 = row[c];
      const int n0   = c * 8;
      const int part = n0 >> 10;            // 0=q 1=k 2=v (uniform per i)
      const int h    = (n0 >> 6) & 15;
      const int d0   = n0 & 63;
      if (part < 2) {
        float f[8];
#pragma unroll
        for (int j = 0; j < 8; ++j) f[j] = bf2f(cv.s[j]);
        const int p0 = d0 >> 1;
        const float4 csA = *(const float4*)(tab + (t << 5) + p0);
        const float4 csB = *(const float4*)(tab + (t << 5) + p0 + 2);
        const float cs[4] = {csA.x, csA.z, csB.x, csB.z};
        const float sn[4] = {csA.y, csA.w, csB.y, csB.w};
#pragma unroll
        for (int j = 0; j < 4; ++j) {
          const float x1 = f[2 * j], x2 = f[2 * j + 1];
          cv.s[2 * j]     = f2bf(x1 * cs[j] - x2 * sn[j]);
          cv.s[2 * j + 1] = f2bf(x2 * cs[j] + x1 * sn[j]);
        }
      }
      unsigned short* dst = QB + part * (16 * 72) + h * 72 + d0;
      *(uint4*)dst = cv.u4;
    }
  }
  // wave-local LDS drain (each wave reads only its own slices — no barrier)
  asm volatile("s_waitcnt lgkmcnt(0)" ::: "memory");
  __builtin_amdgcn_sched_barrier(0);

  // ---- scores both tokens: S^T = K . Q^T via 2x mfma_16x16x32 each ----
  floatx4 accS[2];
#pragma unroll
  for (int tk = 0; tk < 2; ++tk) {
    floatx4 a = {0.f, 0.f, 0.f, 0.f};
    const unsigned short* QB = sQKV[wave][tk];
    const unsigned short* KB = QB + 16 * 72;
#pragma unroll
    for (int half = 0; half < 2; ++half) {
      const bf16x8 kf = *(const bf16x8*)(KB + lm * 72 + half * 32 + quad * 8);
      const bf16x8 qf = *(const bf16x8*)(QB + lm * 72 + half * 32 + quad * 8);
      a = __builtin_amdgcn_mfma_f32_16x16x32_bf16(kf, qf, a, 0, 0, 0);
    }
    accS[tk] = a;
  }

  // ---- softmax both tokens (independent shfl chains interleave) ----
  float s4[2][4], inv[2];
#pragma unroll
  for (int tk = 0; tk < 2; ++tk) {
    float mx = -1e30f;
#pragma unroll
    for (int j = 0; j < 4; ++j) {
      s4[tk][j] = accS[tk][j] * 0.125f;
      mx = fmaxf(mx, s4[tk][j]);
    }
    mx = fmaxf(mx, __shfl_xor(mx, 16, 64));
    mx = fmaxf(mx, __shfl_xor(mx, 32, 64));
    float sum = 0.f;
#pragma unroll
    for (int j = 0; j < 4; ++j) { s4[tk][j] = __expf(s4[tk][j] - mx); sum += s4[tk][j]; }
    sum += __shfl_xor(sum, 16, 64);
    sum += __shfl_xor(sum, 32, 64);
    inv[tk] = 1.0f / sum;
  }

#if PV_MFMA
  // ---- PV via mfma_16x16x16 (S^T C-layout == P A-layout), both tokens ----
  union { short4v v; unsigned short s[4]; } pf[2];
#pragma unroll
  for (int tk = 0; tk < 2; ++tk)
#pragma unroll
    for (int j = 0; j < 4; ++j) {
      const float p = s4[tk][j] * inv[tk];
      pf[tk].s[j] = p == 0.f ? 0 : f2bf(p);
    }
#pragma unroll
  for (int dtile = 0; dtile < 4; ++dtile) {
#pragma unroll
    for (int tk = 0; tk < 2; ++tk) {
      const unsigned short* VB = sQKV[wave][tk] + 2 * 16 * 72;
      union { short4v v; unsigned short s[4]; } vf;
#pragma unroll
      for (int j = 0; j < 4; ++j)
        vf.s[j] = VB[(quad * 4 + j) * 72 + dtile * 16 + lm];
      floatx4 accO = {0.f, 0.f, 0.f, 0.f};
      accO = PV_MFMA_CALL(pf[tk].v, vf.v, accO);
      const int t = tA[tk];
      const int col = (t & 15) * 64 + dtile * 16 + lm;
#pragma unroll
      for (int r = 0; r < 4; ++r) {
        const size_t rr = (size_t)bA[tk] * TT + (size_t)(quad * 4 + r) * 512 + (t >> 4);
        Y[rr * 1024 + col] = f2bf(accO[r]);
      }
    }
  }
#else
  // ---- VALU fallback: P via small LDS, V read as bf16 b128 ----
#pragma unroll
  for (int tk = 0; tk < 2; ++tk) {
    float* P = sP[wave][tk];
    const unsigned short* VB = sQKV[wave][tk] + 2 * 16 * 72;
    const int t = tA[tk];
#pragma unroll
    for (int j = 0; j < 4; ++j) P[(quad * 4 + j) * 16 + lm] = s4[tk][j] * inv[tk];
    asm volatile("s_waitcnt lgkmcnt(0)" ::: "memory");
    __builtin_amdgcn_sched_barrier(0);
    float o[16];
#pragma unroll
    for (int dd = 0; dd < 16; ++dd) o[dd] = 0.f;
#pragma unroll
    for (int kh = 0; kh < 16; ++kh) {
      const float a = P[kh * 16 + lm];
      union { uint4 u4; unsigned short s[8]; } v0, v1;
      v0.u4 = *(const uint4*)(VB + kh * 72 + quad * 16);
      v1.u4 = *(const uint4*)(VB + kh * 72 + quad * 16 + 8);
#pragma unroll
      for (int dd = 0; dd < 8; ++dd) {
        o[dd]     += a * bf2f(v0.s[dd]);
        o[dd + 8] += a * bf2f(v1.s[dd]);
      }
    }
    const size_t rr = (size_t)bA[tk] * TT + (size_t)lm * 512 + (t >> 4);
    unsigned short* yp = Y + rr * 1024 + (t & 15) * 64 + quad * 16;
    union { uint4 u4; unsigned short s[8]; } o1, o2;
#pragma unroll
    for (int dd = 0; dd < 8; ++dd) o1.s[dd] = f2bf(o[dd]);
#pragma unroll
    for (int dd = 0; dd < 8; ++dd) o2.s[dd] = f2bf(o[8 + dd]);
    ((uint4*)yp)[0] = o1.u4;
    ((uint4*)yp)[1] = o2.u4;
  }
#endif
}

// ---------------------------------------------------------------------------
extern "C" void kernel_launch(void* const* d_in, const int* in_sizes, int n_in,
                              void* d_out, int out_size, void* d_ws, size_t ws_size,
                              hipStream_t stream) {
  const float* x    = (const float*)d_in[0];  // (2,8192,1024) fp32
  const float* Wqkv = (const float*)d_in[1];  // (3072,1024)  fp32
  const float* Wout = (const float*)d_in[2];  // (1024,1024)  fp32
  float* out = (float*)d_out;                 // (2,8192,1024) fp32

  // ws (56 MiB, proven): Y 32 | Wqkvb 6 | Woutb 2 | xb 16
  // d_out (67.1 MB): qkv chunk 50.3 MB at 0, rope table 2 MiB at +52 MiB.
  unsigned short* Y     = (unsigned short*)d_ws;
  unsigned short* Wqkvb = Y + (size_t)BT * 1024;
  unsigned short* Woutb = Wqkvb + (size_t)3072 * 1024;
  unsigned short* xb    = Woutb + (size_t)1024 * 1024;
  unsigned short* qkvC  = (unsigned short*)d_out;
  float2* tab           = (float2*)((char*)d_out + (size_t)52 * 1024 * 1024);

  // merged prep: rope table (1024 blocks) + Wqkv cvt (3072) + Wout cvt (1024)
  prep_k<<<dim3(5120), dim3(256), 0, stream>>>(Wqkv, Wout, Wqkvb, Woutb, tab);

  for (int base = 0; base < BT; base += MCH) {
    cvt_f2b<<<dim3(MCH * 1024 / 4 / 256), dim3(256), 0, stream>>>(
        x + (size_t)base * 1024, xb, MCH * 1024 / 4);
    gemm_k32<false><<<dim3((MCH / 256) * (3072 / 128)), dim3(512), 0, stream>>>(
        xb, Wqkvb, qkvC, MCH, 3072, 1024);
    attn_rope_k<<<dim3(MCH / 4), dim3(128), 0, stream>>>(qkvC, tab, Y, base);
  }

  // out = Y @ Wout^T : M=16384, N=1024, K=1024 (fp32 output)
  gemm_k32<true><<<dim3((BT / 256) * (1024 / 128)), dim3(512), 0, stream>>>(
      Y, Woutb, out, BT, 1024, 1024);
}